// Round 9
// baseline (553.599 us; speedup 1.0000x reference)
//
#include <hip/hip_runtime.h>
#include <hip/hip_bf16.h>

#define NN 100000      // nodes
#define DF 128         // feature dim
#define NT 3           // edge types
#define NE 1000000     // edges per type
#define DOUT 512       // DF * (1 + NT)
#define TOTH (NT * NN) // 300000 (type, node) bins
#define NXCD 8
#define SLICE_BINS (TOTH / NXCD)         // 37500
#define NBKT 6000                        // coarse buckets
#define BPB  (TOTH / NBKT)               // 50 bins per bucket
#define BCAP 704                         // bucket capacity: Poisson(500) +9 sigma
#define CVT_BLOCKS (NN * DF / 2 / 256)   // 25000, divisible by 8
#define SCAN_CHUNK 1024
#define NB1 ((TOTH + SCAN_CHUNK - 1) / SCAN_CHUNK)

// ---------------- common small kernels ----------------

__global__ __launch_bounds__(256) void zero_k(int* __restrict__ p, int n) {
    int i = blockIdx.x * 256 + threadIdx.x;
    if (i < n) p[i] = 0;
}

// x (f32) -> bf16 (fallback path).
__global__ __launch_bounds__(256) void cvt_k(const float2* __restrict__ x2,
                                             unsigned int* __restrict__ xh) {
    int i = blockIdx.x * 256 + threadIdx.x;
    if (i >= NN * DF / 2) return;
    float2 v = x2[i];
    __hip_bfloat162 h = __float22bfloat162_rn(v);
    xh[i] = *(unsigned int*)&h;
}

// ---------------- fast path phase A: cvt + sliced bucket-append ----------
// Blocks [0, CVT_BLOCKS): f32->bf16 convert (pure BW).
// Rest: slice = (blockIdx-CVT_BLOCKS)&7 tracks round-robin block->XCD mapping
// (CVT_BLOCKS % 8 == 0); each slice owns a contiguous 1/8 of bin space, so a
// bucket's append region is written from one XCD only, densely in time ->
// each 64B line goes to HBM once (kills round-8's 188MB write amplification).
__global__ __launch_bounds__(256) void buildA_k(const float2* __restrict__ x2,
                                                unsigned int* __restrict__ xh,
                                                const int4* __restrict__ edges4,
                                                int* __restrict__ cur,
                                                int2* __restrict__ append) {
    if (blockIdx.x < CVT_BLOCKS) {
        int i = blockIdx.x * 256 + threadIdx.x;
        float2 v = x2[i];
        __hip_bfloat162 h = __float22bfloat162_rn(v);
        xh[i] = *(unsigned int*)&h;
        return;
    }
    int b = blockIdx.x - CVT_BLOCKS;
    int slice = b & (NXCD - 1);
    int i = (b >> 3) * 256 + threadIdx.x;
    if (i >= NT * NE / 4) return;
    int t = i / (NE / 4);
    int e4 = i - t * (NE / 4);
    int4 sv = edges4[(size_t)(2 * t) * (NE / 4) + e4];
    int4 dv = edges4[(size_t)(2 * t + 1) * (NE / 4) + e4];
    int b0 = t * NN;
    int bin;
    bin = b0 + dv.x; if (bin / SLICE_BINS == slice) { int bk = bin / BPB; int p = atomicAdd(&cur[bk], 1); if (p < BCAP) append[(size_t)bk * BCAP + p] = make_int2(sv.x, bin); }
    bin = b0 + dv.y; if (bin / SLICE_BINS == slice) { int bk = bin / BPB; int p = atomicAdd(&cur[bk], 1); if (p < BCAP) append[(size_t)bk * BCAP + p] = make_int2(sv.y, bin); }
    bin = b0 + dv.z; if (bin / SLICE_BINS == slice) { int bk = bin / BPB; int p = atomicAdd(&cur[bk], 1); if (p < BCAP) append[(size_t)bk * BCAP + p] = make_int2(sv.z, bin); }
    bin = b0 + dv.w; if (bin / SLICE_BINS == slice) { int bk = bin / BPB; int p = atomicAdd(&cur[bk], 1); if (p < BCAP) append[(size_t)bk * BCAP + p] = make_int2(sv.w, bin); }
}

// ---------------- fast path phase B: bucket -> packed per-bin CSR ---------
// One block per bucket: stage entries in LDS, count per bin, exclusive scan
// (serial 50 elems by thread 0 -- negligible), scatter packed into srcS,
// emit cnt/offs. All global writes are block-local contiguous regions.
__global__ __launch_bounds__(256) void buildB_k(const int* __restrict__ cur,
                                                const int2* __restrict__ append,
                                                int* __restrict__ srcS,
                                                int* __restrict__ cnt,
                                                int* __restrict__ offs) {
    __shared__ int2 s_ent[BCAP];
    __shared__ int lcnt[64], lofs[64], lcur[64];
    int bkt = blockIdx.x;
    int tid = threadIdx.x;
    int nb = cur[bkt]; if (nb > BCAP) nb = BCAP;
    if (tid < 64) { lcnt[tid] = 0; lcur[tid] = 0; }
    for (int i = tid; i < nb; i += 256) s_ent[i] = append[(size_t)bkt * BCAP + i];
    __syncthreads();
    int binBase = bkt * BPB;
    for (int i = tid; i < nb; i += 256) atomicAdd(&lcnt[s_ent[i].y - binBase], 1);
    __syncthreads();
    if (tid == 0) {
        int run = 0;
        for (int j = 0; j < BPB; j++) { lofs[j] = run; run += lcnt[j]; }
    }
    __syncthreads();
    for (int i = tid; i < nb; i += 256) {
        int lbin = s_ent[i].y - binBase;
        int pos = lofs[lbin] + atomicAdd(&lcur[lbin], 1);
        srcS[(size_t)bkt * BCAP + pos] = s_ent[i].x;
    }
    if (tid < BPB) {
        cnt[binBase + tid] = lcnt[tid];
        offs[binBase + tid] = bkt * BCAP + lofs[tid];
    }
}

// ---------------- fast-path gather: packed CSR + shfl src broadcast -------
// One 64-lane wave per unit. Waves [0, NN/2): copy 2 raw rows (exact f32).
// Waves [NN/2, NN/2+TOTH): mean-agg one bin. srcv = srcS[base+lane] loaded
// guarded (lane < c); shfl sources always < cl <= c so all source lanes hold
// valid data and all 64 lanes are active at every shfl (equal trip counts:
// ceven = cl & ~1). Odd tail: uniform shfl of cl-1, half 0 accumulates.
// c > 64 tail (never for this input): direct scalar loads, no cross-lane ops.
__global__ __launch_bounds__(256) void gather_pad_k(const float4* __restrict__ x4,
                                                    const uint2* __restrict__ xh2,
                                                    const int* __restrict__ cnt,
                                                    const int* __restrict__ offs,
                                                    const int* __restrict__ srcS,
                                                    float4* __restrict__ out4) {
    int gtid = blockIdx.x * 256 + threadIdx.x;
    int w = gtid >> 6;
    int lane = threadIdx.x & 63;
    int half = lane >> 5;
    int col = lane & 31;
    if (w < NN / 2) {
        int n = 2 * w + half;
        out4[(size_t)n * (DOUT / 4) + col] = x4[(size_t)n * (DF / 4) + col];
        return;
    }
    int a = w - NN / 2;
    if (a >= TOTH) return;
    int t = a / NN;
    int n = a - t * NN;
    int c = cnt[a];
    int base = offs[a];
    int srcv = 0;
    if (lane < c) srcv = srcS[base + lane];
    float4 acc = make_float4(0.f, 0.f, 0.f, 0.f);
    int cl = c < 64 ? c : 64;
    int ceven = cl & ~1;
    int k = half;
    for (; k + 6 < ceven; k += 8) {
        int s0 = __shfl(srcv, k, 64);
        int s1 = __shfl(srcv, k + 2, 64);
        int s2 = __shfl(srcv, k + 4, 64);
        int s3 = __shfl(srcv, k + 6, 64);
        uint2 u0 = xh2[(size_t)s0 * 32 + col];
        uint2 u1 = xh2[(size_t)s1 * 32 + col];
        uint2 u2 = xh2[(size_t)s2 * 32 + col];
        uint2 u3 = xh2[(size_t)s3 * 32 + col];
        float2 p;
        p = __bfloat1622float2(*(__hip_bfloat162*)&u0.x); acc.x += p.x; acc.y += p.y;
        p = __bfloat1622float2(*(__hip_bfloat162*)&u0.y); acc.z += p.x; acc.w += p.y;
        p = __bfloat1622float2(*(__hip_bfloat162*)&u1.x); acc.x += p.x; acc.y += p.y;
        p = __bfloat1622float2(*(__hip_bfloat162*)&u1.y); acc.z += p.x; acc.w += p.y;
        p = __bfloat1622float2(*(__hip_bfloat162*)&u2.x); acc.x += p.x; acc.y += p.y;
        p = __bfloat1622float2(*(__hip_bfloat162*)&u2.y); acc.z += p.x; acc.w += p.y;
        p = __bfloat1622float2(*(__hip_bfloat162*)&u3.x); acc.x += p.x; acc.y += p.y;
        p = __bfloat1622float2(*(__hip_bfloat162*)&u3.y); acc.z += p.x; acc.w += p.y;
    }
    for (; k < ceven; k += 2) {
        int s0 = __shfl(srcv, k, 64);
        uint2 u0 = xh2[(size_t)s0 * 32 + col];
        float2 p;
        p = __bfloat1622float2(*(__hip_bfloat162*)&u0.x); acc.x += p.x; acc.y += p.y;
        p = __bfloat1622float2(*(__hip_bfloat162*)&u0.y); acc.z += p.x; acc.w += p.y;
    }
    if (cl & 1) {
        int s0 = __shfl(srcv, cl - 1, 64);   // uniform: all 64 lanes execute
        if (half == 0) {
            uint2 u0 = xh2[(size_t)s0 * 32 + col];
            float2 p;
            p = __bfloat1622float2(*(__hip_bfloat162*)&u0.x); acc.x += p.x; acc.y += p.y;
            p = __bfloat1622float2(*(__hip_bfloat162*)&u0.y); acc.z += p.x; acc.w += p.y;
        }
    }
    for (int q = cl + half; q < c; q += 2) {   // c > 64 only; no cross-lane ops
        int s0 = srcS[base + q];
        uint2 u0 = xh2[(size_t)s0 * 32 + col];
        float2 p;
        p = __bfloat1622float2(*(__hip_bfloat162*)&u0.x); acc.x += p.x; acc.y += p.y;
        p = __bfloat1622float2(*(__hip_bfloat162*)&u0.y); acc.z += p.x; acc.w += p.y;
    }
    acc.x += __shfl_xor(acc.x, 32, 64);
    acc.y += __shfl_xor(acc.y, 32, 64);
    acc.z += __shfl_xor(acc.z, 32, 64);
    acc.w += __shfl_xor(acc.w, 32, 64);
    if (half == 0) {
        float sc = (c > 0) ? 1.0f / (float)c : 0.0f;
        acc.x *= sc; acc.y *= sc; acc.z *= sc; acc.w *= sc;
        out4[(size_t)n * (DOUT / 4) + (DF / 4) + t * (DF / 4) + col] = acc;
    }
}

// ---------------- fallback: CSR build + scalar-load gather (round-7 proven) --

__global__ __launch_bounds__(256) void hist_k(const int4* __restrict__ edges4,
                                              int* __restrict__ hist) {
    int i = blockIdx.x * 256 + threadIdx.x;
    if (i >= NT * NE / 4) return;
    int t = i / (NE / 4);
    int e4 = i - t * (NE / 4);
    int4 d = edges4[(size_t)(2 * t + 1) * (NE / 4) + e4];
    atomicAdd(&hist[t * NN + d.x], 1);
    atomicAdd(&hist[t * NN + d.y], 1);
    atomicAdd(&hist[t * NN + d.z], 1);
    atomicAdd(&hist[t * NN + d.w], 1);
}

__global__ __launch_bounds__(256) void scan1_k(const int* __restrict__ hist,
                                               int* __restrict__ offs,
                                               int* __restrict__ bsum) {
    __shared__ int s[256];
    int tid = threadIdx.x;
    int base = blockIdx.x * SCAN_CHUNK + tid * 4;
    int v0 = 0, v1 = 0, v2 = 0, v3 = 0;
    if (base + 0 < TOTH) v0 = hist[base + 0];
    if (base + 1 < TOTH) v1 = hist[base + 1];
    if (base + 2 < TOTH) v2 = hist[base + 2];
    if (base + 3 < TOTH) v3 = hist[base + 3];
    int sum = v0 + v1 + v2 + v3;
    s[tid] = sum;
    __syncthreads();
    for (int off = 1; off < 256; off <<= 1) {
        int t = (tid >= off) ? s[tid - off] : 0;
        __syncthreads();
        s[tid] += t;
        __syncthreads();
    }
    int run = s[tid] - sum;
    if (tid == 255) bsum[blockIdx.x] = s[255];
    if (base + 0 < TOTH) { offs[base + 0] = run; run += v0; }
    if (base + 1 < TOTH) { offs[base + 1] = run; run += v1; }
    if (base + 2 < TOTH) { offs[base + 2] = run; run += v2; }
    if (base + 3 < TOTH) { offs[base + 3] = run; run += v3; }
}

__global__ __launch_bounds__(512) void scan2_k(int* __restrict__ bsum) {
    __shared__ int s[512];
    int tid = threadIdx.x;
    int v = (tid < NB1) ? bsum[tid] : 0;
    s[tid] = v;
    __syncthreads();
    for (int off = 1; off < 512; off <<= 1) {
        int t = (tid >= off) ? s[tid - off] : 0;
        __syncthreads();
        s[tid] += t;
        __syncthreads();
    }
    if (tid < NB1) bsum[tid] = s[tid] - v;
}

__global__ __launch_bounds__(256) void scan3_k(int* __restrict__ offs,
                                               const int* __restrict__ bsum) {
    int i = blockIdx.x * 256 + threadIdx.x;
    if (i < TOTH) offs[i] += bsum[i / SCAN_CHUNK];
}

__global__ __launch_bounds__(256) void fill_csr_k(const int4* __restrict__ edges4,
                                                  int* __restrict__ offs,
                                                  int* __restrict__ srcS) {
    int slice = blockIdx.x & (NXCD - 1);
    int i = (blockIdx.x >> 3) * 256 + threadIdx.x;
    if (i >= NT * NE / 4) return;
    int t = i / (NE / 4);
    int e4 = i - t * (NE / 4);
    int4 sv = edges4[(size_t)(2 * t) * (NE / 4) + e4];
    int4 dv = edges4[(size_t)(2 * t + 1) * (NE / 4) + e4];
    int b0 = t * NN;
    int bin;
    bin = b0 + dv.x; if (bin / SLICE_BINS == slice) srcS[atomicAdd(&offs[bin], 1)] = sv.x;
    bin = b0 + dv.y; if (bin / SLICE_BINS == slice) srcS[atomicAdd(&offs[bin], 1)] = sv.y;
    bin = b0 + dv.z; if (bin / SLICE_BINS == slice) srcS[atomicAdd(&offs[bin], 1)] = sv.z;
    bin = b0 + dv.w; if (bin / SLICE_BINS == slice) srcS[atomicAdd(&offs[bin], 1)] = sv.w;
}

template <int USE_BF16>
__global__ __launch_bounds__(256) void gather_k(const float4* __restrict__ x4,
                                                const uint2* __restrict__ xh2,
                                                const int* __restrict__ cnt,
                                                const int* __restrict__ offs,
                                                const int* __restrict__ srcS,
                                                float4* __restrict__ out4) {
    int gtid = blockIdx.x * 256 + threadIdx.x;
    int w = gtid >> 6;
    int lane = threadIdx.x & 63;
    int half = lane >> 5;
    int col = lane & 31;
    if (w < NN / 2) {
        int n = 2 * w + half;
        out4[(size_t)n * (DOUT / 4) + col] = x4[(size_t)n * (DF / 4) + col];
        return;
    }
    int a = w - NN / 2;
    if (a >= TOTH) return;
    int t = a / NN;
    int n = a - t * NN;
    int c = cnt[a];
    int base = offs[a] - c;
    float4 acc = make_float4(0.f, 0.f, 0.f, 0.f);
    int k = half;
    for (; k + 6 < c; k += 8) {
        int s0 = srcS[base + k];
        int s1 = srcS[base + k + 2];
        int s2 = srcS[base + k + 4];
        int s3 = srcS[base + k + 6];
        if (USE_BF16) {
            uint2 u0 = xh2[(size_t)s0 * 32 + col];
            uint2 u1 = xh2[(size_t)s1 * 32 + col];
            uint2 u2 = xh2[(size_t)s2 * 32 + col];
            uint2 u3 = xh2[(size_t)s3 * 32 + col];
            float2 p;
            p = __bfloat1622float2(*(__hip_bfloat162*)&u0.x); acc.x += p.x; acc.y += p.y;
            p = __bfloat1622float2(*(__hip_bfloat162*)&u0.y); acc.z += p.x; acc.w += p.y;
            p = __bfloat1622float2(*(__hip_bfloat162*)&u1.x); acc.x += p.x; acc.y += p.y;
            p = __bfloat1622float2(*(__hip_bfloat162*)&u1.y); acc.z += p.x; acc.w += p.y;
            p = __bfloat1622float2(*(__hip_bfloat162*)&u2.x); acc.x += p.x; acc.y += p.y;
            p = __bfloat1622float2(*(__hip_bfloat162*)&u2.y); acc.z += p.x; acc.w += p.y;
            p = __bfloat1622float2(*(__hip_bfloat162*)&u3.x); acc.x += p.x; acc.y += p.y;
            p = __bfloat1622float2(*(__hip_bfloat162*)&u3.y); acc.z += p.x; acc.w += p.y;
        } else {
            float4 v0 = x4[(size_t)s0 * (DF / 4) + col];
            float4 v1 = x4[(size_t)s1 * (DF / 4) + col];
            float4 v2 = x4[(size_t)s2 * (DF / 4) + col];
            float4 v3 = x4[(size_t)s3 * (DF / 4) + col];
            acc.x += v0.x + v1.x + v2.x + v3.x;
            acc.y += v0.y + v1.y + v2.y + v3.y;
            acc.z += v0.z + v1.z + v2.z + v3.z;
            acc.w += v0.w + v1.w + v2.w + v3.w;
        }
    }
    for (; k < c; k += 2) {
        int s0 = srcS[base + k];
        if (USE_BF16) {
            uint2 u0 = xh2[(size_t)s0 * 32 + col];
            float2 p;
            p = __bfloat1622float2(*(__hip_bfloat162*)&u0.x); acc.x += p.x; acc.y += p.y;
            p = __bfloat1622float2(*(__hip_bfloat162*)&u0.y); acc.z += p.x; acc.w += p.y;
        } else {
            float4 v0 = x4[(size_t)s0 * (DF / 4) + col];
            acc.x += v0.x; acc.y += v0.y; acc.z += v0.z; acc.w += v0.w;
        }
    }
    acc.x += __shfl_xor(acc.x, 32, 64);
    acc.y += __shfl_xor(acc.y, 32, 64);
    acc.z += __shfl_xor(acc.z, 32, 64);
    acc.w += __shfl_xor(acc.w, 32, 64);
    if (half == 0) {
        float sc = (c > 0) ? 1.0f / (float)c : 0.0f;
        acc.x *= sc; acc.y *= sc; acc.z *= sc; acc.w *= sc;
        out4[(size_t)n * (DOUT / 4) + (DF / 4) + t * (DF / 4) + col] = acc;
    }
}

extern "C" void kernel_launch(void* const* d_in, const int* in_sizes, int n_in,
                              void* d_out, int out_size, void* d_ws, size_t ws_size,
                              hipStream_t stream) {
    const float* x = (const float*)d_in[0];
    const int* edges = (const int*)d_in[1];
    float4* out4 = (float4*)d_out;

    const int covBlocks = (TOTH + 255) / 256;
    const int edge4Blocks = (NT * NE / 4 + 255) / 256;  // 2930
    const int nWaves = NN / 2 + TOTH;
    const int gatherBlocks = (nWaves + 3) / 4;
    const int cvtBlocks = CVT_BLOCKS;

    // fast path layout (ints): cur[NBKT] | append[NBKT*BCAP int2] | xh[NN*DF/2]
    //                          | srcS[NBKT*BCAP + 64] | cnt[TOTH] | offs[TOTH]
    size_t fastInts = (size_t)NBKT + (size_t)NBKT * BCAP * 2 + (size_t)NN * DF / 2 +
                      (size_t)NBKT * BCAP + 64 + 2 * (size_t)TOTH;
    size_t needFast = fastInts * 4;                     // ~78.7 MB
    // CSR path:  hist | offs | bsum[1024] | xh | srcS[NT*NE+64]  (~40 MB)
    size_t needBf = ((size_t)2 * TOTH + 1024 + (size_t)NN * DF / 2 +
                     (size_t)NT * NE + 64) * 4;

    if (ws_size >= needFast) {
        int* cur = (int*)d_ws;                              // NBKT
        int2* append = (int2*)(cur + NBKT);                 // NBKT*BCAP int2
        unsigned int* xh = (unsigned int*)(cur + NBKT + (size_t)NBKT * BCAP * 2);
        int* srcS = (int*)(xh + (size_t)NN * DF / 2);       // NBKT*BCAP + 64
        int* cnt = srcS + (size_t)NBKT * BCAP + 64;         // TOTH
        int* offs = cnt + TOTH;                             // TOTH
        hipLaunchKernelGGL(zero_k, dim3((NBKT + 255) / 256), dim3(256), 0, stream,
                           cur, NBKT);
        hipLaunchKernelGGL(buildA_k, dim3(cvtBlocks + edge4Blocks * NXCD), dim3(256),
                           0, stream, (const float2*)x, xh, (const int4*)edges,
                           cur, append);
        hipLaunchKernelGGL(buildB_k, dim3(NBKT), dim3(256), 0, stream,
                           cur, append, srcS, cnt, offs);
        hipLaunchKernelGGL(gather_pad_k, dim3(gatherBlocks), dim3(256), 0, stream,
                           (const float4*)x, (const uint2*)xh, cnt, offs, srcS, out4);
        return;
    }

    int* hist = (int*)d_ws;
    int* offs = hist + TOTH;
    int* bsum = offs + TOTH;
    bool useBf = ws_size >= needBf;
    unsigned int* xh = (unsigned int*)(bsum + 1024);
    int* srcS = useBf ? (int*)(xh + (size_t)NN * DF / 2) : (int*)(bsum + 1024);

    hipLaunchKernelGGL(zero_k, dim3(covBlocks), dim3(256), 0, stream, hist, TOTH);
    hipLaunchKernelGGL(hist_k, dim3(edge4Blocks), dim3(256), 0, stream,
                       (const int4*)edges, hist);
    hipLaunchKernelGGL(scan1_k, dim3(NB1), dim3(256), 0, stream, hist, offs, bsum);
    hipLaunchKernelGGL(scan2_k, dim3(1), dim3(512), 0, stream, bsum);
    hipLaunchKernelGGL(scan3_k, dim3(covBlocks), dim3(256), 0, stream, offs, bsum);
    hipLaunchKernelGGL(fill_csr_k, dim3(edge4Blocks * NXCD), dim3(256), 0, stream,
                       (const int4*)edges, offs, srcS);
    if (useBf) {
        hipLaunchKernelGGL(cvt_k, dim3(cvtBlocks), dim3(256), 0, stream,
                           (const float2*)x, xh);
        hipLaunchKernelGGL((gather_k<1>), dim3(gatherBlocks), dim3(256), 0, stream,
                           (const float4*)x, (const uint2*)xh, hist, offs, srcS, out4);
    } else {
        hipLaunchKernelGGL((gather_k<0>), dim3(gatherBlocks), dim3(256), 0, stream,
                           (const float4*)x, (const uint2*)nullptr, hist, offs, srcS, out4);
    }
}

// Round 10
// 430.978 us; speedup vs baseline: 1.2845x; 1.2845x over previous
//
#include <hip/hip_runtime.h>
#include <hip/hip_bf16.h>

#define NN 100000      // nodes
#define DF 128         // feature dim
#define NT 3           // edge types
#define NE 1000000     // edges per type
#define DOUT 512       // DF * (1 + NT)
#define TOTH (NT * NN) // 300000 (type, node) bins
#define NXCD 8
#define SLICE_BINS (TOTH / NXCD)         // 37500
#define CVT_BLOCKS (NN * DF / 2 / 256)   // 25000
#define EDGE4_BLOCKS ((NT * NE / 4 + 255) / 256)  // 2930
#define SCAN_CHUNK 1024
#define NB1 ((TOTH + SCAN_CHUNK - 1) / SCAN_CHUNK)  // 293

__global__ __launch_bounds__(256) void zero_k(int* __restrict__ p, int n) {
    int i = blockIdx.x * 256 + threadIdx.x;
    if (i < n) p[i] = 0;
}

// ---------------- prep: cvt + raw-copy + hist, one kernel ----------------
// Blocks [0, CVT_BLOCKS): read x once as float2 -> write bf16 xh AND the
// out[:, :128] raw-copy region (gather never touches the copy again).
// Blocks [CVT_BLOCKS, +EDGE4_BLOCKS): per-bin histogram (int4 dst loads,
// 3M atomics on the 1.2MB hist array -- L2-resident).
__global__ __launch_bounds__(256) void prep_k(const float2* __restrict__ x2,
                                              unsigned int* __restrict__ xh,
                                              float2* __restrict__ out2,
                                              const int4* __restrict__ edges4,
                                              int* __restrict__ hist) {
    if (blockIdx.x < CVT_BLOCKS) {
        int i = blockIdx.x * 256 + threadIdx.x;      // i < NN*DF/2
        float2 v = x2[i];
        __hip_bfloat162 h = __float22bfloat162_rn(v);
        xh[i] = *(unsigned int*)&h;
        int n = i >> 6;                               // node
        out2[(size_t)n * (DOUT / 2) + (i & 63)] = v;  // cols 0..127
        return;
    }
    int i = (blockIdx.x - CVT_BLOCKS) * 256 + threadIdx.x;
    if (i >= NT * NE / 4) return;
    int t = i / (NE / 4);
    int e4 = i - t * (NE / 4);
    int4 d = edges4[(size_t)(2 * t + 1) * (NE / 4) + e4];
    atomicAdd(&hist[t * NN + d.x], 1);
    atomicAdd(&hist[t * NN + d.y], 1);
    atomicAdd(&hist[t * NN + d.z], 1);
    atomicAdd(&hist[t * NN + d.w], 1);
}

// ---------------- scans (round-5 proven) ----------------

__global__ __launch_bounds__(256) void scan1_k(const int* __restrict__ hist,
                                               int* __restrict__ offs,
                                               int* __restrict__ bsum) {
    __shared__ int s[256];
    int tid = threadIdx.x;
    int base = blockIdx.x * SCAN_CHUNK + tid * 4;
    int v0 = 0, v1 = 0, v2 = 0, v3 = 0;
    if (base + 0 < TOTH) v0 = hist[base + 0];
    if (base + 1 < TOTH) v1 = hist[base + 1];
    if (base + 2 < TOTH) v2 = hist[base + 2];
    if (base + 3 < TOTH) v3 = hist[base + 3];
    int sum = v0 + v1 + v2 + v3;
    s[tid] = sum;
    __syncthreads();
    for (int off = 1; off < 256; off <<= 1) {
        int t = (tid >= off) ? s[tid - off] : 0;
        __syncthreads();
        s[tid] += t;
        __syncthreads();
    }
    int run = s[tid] - sum;
    if (tid == 255) bsum[blockIdx.x] = s[255];
    if (base + 0 < TOTH) { offs[base + 0] = run; run += v0; }
    if (base + 1 < TOTH) { offs[base + 1] = run; run += v1; }
    if (base + 2 < TOTH) { offs[base + 2] = run; run += v2; }
    if (base + 3 < TOTH) { offs[base + 3] = run; run += v3; }
}

__global__ __launch_bounds__(512) void scan2_k(int* __restrict__ bsum) {
    __shared__ int s[512];
    int tid = threadIdx.x;
    int v = (tid < NB1) ? bsum[tid] : 0;
    s[tid] = v;
    __syncthreads();
    for (int off = 1; off < 512; off <<= 1) {
        int t = (tid >= off) ? s[tid - off] : 0;
        __syncthreads();
        s[tid] += t;
        __syncthreads();
    }
    if (tid < NB1) bsum[tid] = s[tid] - v;
}

__global__ __launch_bounds__(256) void scan3_k(int* __restrict__ offs,
                                               const int* __restrict__ bsum) {
    int i = blockIdx.x * 256 + threadIdx.x;
    if (i < TOTH) offs[i] += bsum[i / SCAN_CHUNK];
}

// ---------------- fill: XCD-sliced packed CSR (round-5 proven) ------------
// Packed srcS = 12 MB -> 1.5 MB per slice: cursor + scatter targets stay
// resident in the owning XCD's L2, so 4B stores merge before HBM writeback.
__global__ __launch_bounds__(256) void fill_csr_k(const int4* __restrict__ edges4,
                                                  int* __restrict__ offs,
                                                  int* __restrict__ srcS) {
    int slice = blockIdx.x & (NXCD - 1);
    int i = (blockIdx.x >> 3) * 256 + threadIdx.x;
    if (i >= NT * NE / 4) return;
    int t = i / (NE / 4);
    int e4 = i - t * (NE / 4);
    int4 sv = edges4[(size_t)(2 * t) * (NE / 4) + e4];
    int4 dv = edges4[(size_t)(2 * t + 1) * (NE / 4) + e4];
    int b0 = t * NN;
    int bin;
    bin = b0 + dv.x; if (bin / SLICE_BINS == slice) srcS[atomicAdd(&offs[bin], 1)] = sv.x;
    bin = b0 + dv.y; if (bin / SLICE_BINS == slice) srcS[atomicAdd(&offs[bin], 1)] = sv.y;
    bin = b0 + dv.z; if (bin / SLICE_BINS == slice) srcS[atomicAdd(&offs[bin], 1)] = sv.z;
    bin = b0 + dv.w; if (bin / SLICE_BINS == slice) srcS[atomicAdd(&offs[bin], 1)] = sv.w;
}

// ---------------- gather: agg-only, packed CSR, 4-deep ILP ----------------
// One 64-lane wave per bin. Lanes 0-31 even edges, 32-63 odd; 4 independent
// bf16 row loads in flight per half; halves combined via shfl_xor(32) with
// all lanes active (loop bounds identical across the wave). No copy waves --
// the raw-copy region was written by prep_k.
__global__ __launch_bounds__(256) void gather_agg_k(const uint2* __restrict__ xh2,
                                                    const int* __restrict__ cnt,
                                                    const int* __restrict__ offs,
                                                    const int* __restrict__ srcS,
                                                    float4* __restrict__ out4) {
    int gtid = blockIdx.x * 256 + threadIdx.x;
    int a = gtid >> 6;
    if (a >= TOTH) return;
    int lane = threadIdx.x & 63;
    int half = lane >> 5;
    int col = lane & 31;
    int t = a / NN;
    int n = a - t * NN;
    int c = cnt[a];
    int base = offs[a] - c;   // offs is the end cursor after fill
    float4 acc = make_float4(0.f, 0.f, 0.f, 0.f);
    int k = half;
    for (; k + 6 < c; k += 8) {
        int s0 = srcS[base + k];
        int s1 = srcS[base + k + 2];
        int s2 = srcS[base + k + 4];
        int s3 = srcS[base + k + 6];
        uint2 u0 = xh2[(size_t)s0 * 32 + col];
        uint2 u1 = xh2[(size_t)s1 * 32 + col];
        uint2 u2 = xh2[(size_t)s2 * 32 + col];
        uint2 u3 = xh2[(size_t)s3 * 32 + col];
        float2 p;
        p = __bfloat1622float2(*(__hip_bfloat162*)&u0.x); acc.x += p.x; acc.y += p.y;
        p = __bfloat1622float2(*(__hip_bfloat162*)&u0.y); acc.z += p.x; acc.w += p.y;
        p = __bfloat1622float2(*(__hip_bfloat162*)&u1.x); acc.x += p.x; acc.y += p.y;
        p = __bfloat1622float2(*(__hip_bfloat162*)&u1.y); acc.z += p.x; acc.w += p.y;
        p = __bfloat1622float2(*(__hip_bfloat162*)&u2.x); acc.x += p.x; acc.y += p.y;
        p = __bfloat1622float2(*(__hip_bfloat162*)&u2.y); acc.z += p.x; acc.w += p.y;
        p = __bfloat1622float2(*(__hip_bfloat162*)&u3.x); acc.x += p.x; acc.y += p.y;
        p = __bfloat1622float2(*(__hip_bfloat162*)&u3.y); acc.z += p.x; acc.w += p.y;
    }
    for (; k < c; k += 2) {
        int s0 = srcS[base + k];
        uint2 u0 = xh2[(size_t)s0 * 32 + col];
        float2 p;
        p = __bfloat1622float2(*(__hip_bfloat162*)&u0.x); acc.x += p.x; acc.y += p.y;
        p = __bfloat1622float2(*(__hip_bfloat162*)&u0.y); acc.z += p.x; acc.w += p.y;
    }
    acc.x += __shfl_xor(acc.x, 32, 64);
    acc.y += __shfl_xor(acc.y, 32, 64);
    acc.z += __shfl_xor(acc.z, 32, 64);
    acc.w += __shfl_xor(acc.w, 32, 64);
    if (half == 0) {
        float sc = (c > 0) ? 1.0f / (float)c : 0.0f;
        acc.x *= sc; acc.y *= sc; acc.z *= sc; acc.w *= sc;
        out4[(size_t)n * (DOUT / 4) + (DF / 4) + t * (DF / 4) + col] = acc;
    }
}

// ---------------- minimal fallback (ws too small): f32 CSR ----------------

__global__ __launch_bounds__(256) void hist_k(const int4* __restrict__ edges4,
                                              int* __restrict__ hist) {
    int i = blockIdx.x * 256 + threadIdx.x;
    if (i >= NT * NE / 4) return;
    int t = i / (NE / 4);
    int e4 = i - t * (NE / 4);
    int4 d = edges4[(size_t)(2 * t + 1) * (NE / 4) + e4];
    atomicAdd(&hist[t * NN + d.x], 1);
    atomicAdd(&hist[t * NN + d.y], 1);
    atomicAdd(&hist[t * NN + d.z], 1);
    atomicAdd(&hist[t * NN + d.w], 1);
}

__global__ __launch_bounds__(256) void gather_f32_k(const float4* __restrict__ x4,
                                                    const int* __restrict__ cnt,
                                                    const int* __restrict__ offs,
                                                    const int* __restrict__ srcS,
                                                    float4* __restrict__ out4) {
    int gtid = blockIdx.x * 256 + threadIdx.x;
    int w = gtid >> 6;
    int lane = threadIdx.x & 63;
    int half = lane >> 5;
    int col = lane & 31;
    if (w < NN / 2) {
        int n = 2 * w + half;
        out4[(size_t)n * (DOUT / 4) + col] = x4[(size_t)n * (DF / 4) + col];
        return;
    }
    int a = w - NN / 2;
    if (a >= TOTH) return;
    int t = a / NN;
    int n = a - t * NN;
    int c = cnt[a];
    int base = offs[a] - c;
    float4 acc = make_float4(0.f, 0.f, 0.f, 0.f);
    for (int k = half; k < c; k += 2) {
        int s0 = srcS[base + k];
        float4 v0 = x4[(size_t)s0 * (DF / 4) + col];
        acc.x += v0.x; acc.y += v0.y; acc.z += v0.z; acc.w += v0.w;
    }
    acc.x += __shfl_xor(acc.x, 32, 64);
    acc.y += __shfl_xor(acc.y, 32, 64);
    acc.z += __shfl_xor(acc.z, 32, 64);
    acc.w += __shfl_xor(acc.w, 32, 64);
    if (half == 0) {
        float sc = (c > 0) ? 1.0f / (float)c : 0.0f;
        acc.x *= sc; acc.y *= sc; acc.z *= sc; acc.w *= sc;
        out4[(size_t)n * (DOUT / 4) + (DF / 4) + t * (DF / 4) + col] = acc;
    }
}

extern "C" void kernel_launch(void* const* d_in, const int* in_sizes, int n_in,
                              void* d_out, int out_size, void* d_ws, size_t ws_size,
                              hipStream_t stream) {
    const float* x = (const float*)d_in[0];
    const int* edges = (const int*)d_in[1];
    float4* out4 = (float4*)d_out;

    const int covBlocks = (TOTH + 255) / 256;           // 1172
    const int aggBlocks = (TOTH * 64 + 255) / 256;      // 75000

    // layout (ints): hist[TOTH] | offs[TOTH] | bsum[1024] | xh[NN*DF/2]
    //                | srcS[NT*NE + 64]   (~40.1 MB)
    int* hist = (int*)d_ws;
    int* offs = hist + TOTH;
    int* bsum = offs + TOTH;
    unsigned int* xh = (unsigned int*)(bsum + 1024);
    int* srcS = (int*)(xh + (size_t)NN * DF / 2);
    size_t needFast = ((size_t)2 * TOTH + 1024 + (size_t)NN * DF / 2 +
                       (size_t)NT * NE + 64) * 4;

    if (ws_size >= needFast) {
        hipLaunchKernelGGL(zero_k, dim3(covBlocks), dim3(256), 0, stream, hist, TOTH);
        hipLaunchKernelGGL(prep_k, dim3(CVT_BLOCKS + EDGE4_BLOCKS), dim3(256), 0,
                           stream, (const float2*)x, xh, (float2*)d_out,
                           (const int4*)edges, hist);
        hipLaunchKernelGGL(scan1_k, dim3(NB1), dim3(256), 0, stream, hist, offs, bsum);
        hipLaunchKernelGGL(scan2_k, dim3(1), dim3(512), 0, stream, bsum);
        hipLaunchKernelGGL(scan3_k, dim3(covBlocks), dim3(256), 0, stream, offs, bsum);
        hipLaunchKernelGGL(fill_csr_k, dim3(EDGE4_BLOCKS * NXCD), dim3(256), 0, stream,
                           (const int4*)edges, offs, srcS);
        hipLaunchKernelGGL(gather_agg_k, dim3(aggBlocks), dim3(256), 0, stream,
                           (const uint2*)xh, hist, offs, srcS, out4);
        return;
    }

    // fallback: f32 CSR without xh (srcS directly after bsum)
    int* srcS2 = bsum + 1024;
    const int nWaves = NN / 2 + TOTH;
    const int gatherBlocks = (nWaves + 3) / 4;
    hipLaunchKernelGGL(zero_k, dim3(covBlocks), dim3(256), 0, stream, hist, TOTH);
    hipLaunchKernelGGL(hist_k, dim3(EDGE4_BLOCKS), dim3(256), 0, stream,
                       (const int4*)edges, hist);
    hipLaunchKernelGGL(scan1_k, dim3(NB1), dim3(256), 0, stream, hist, offs, bsum);
    hipLaunchKernelGGL(scan2_k, dim3(1), dim3(512), 0, stream, bsum);
    hipLaunchKernelGGL(scan3_k, dim3(covBlocks), dim3(256), 0, stream, offs, bsum);
    hipLaunchKernelGGL(fill_csr_k, dim3(EDGE4_BLOCKS * NXCD), dim3(256), 0, stream,
                       (const int4*)edges, offs, srcS2);
    hipLaunchKernelGGL(gather_f32_k, dim3(gatherBlocks), dim3(256), 0, stream,
                       (const float4*)x, hist, offs, srcS2, out4);
}